// Round 2
// baseline (208.527 us; speedup 1.0000x reference)
//
#include <hip/hip_runtime.h>
#include <stdint.h>

// Problem constants (fixed by the reference file)
#define T_TOTAL  4194304          // B*K*N = 8*4*131072
#define NEG_IDLE (-100000000.0f)
#define NEG_FILL (-1000.0f)

#define BLOCK            256
#define ELEMS_PER_THREAD 16
#define ELEMS_PER_BLOCK  (BLOCK * ELEMS_PER_THREAD)   // 4096
#define NBLOCKS          (T_TOTAL / ELEMS_PER_BLOCK)  // 1024
// N = 131072 = 32 * 4096 -> every block has one uniform (b,k): bk = blk >> 5

// Workspace layout (bytes):
//   [0]                : int flag  (1 = masks are int32, 0 = masks are uint8)
//   [16 .. 16+4K)      : sums_s (1024 int)
//   [16+4K .. 16+8K)   : sums_a (1024 int)
//   [16+8K .. +1MB)    : packed bits, 1 u32 per thread (surf low16 | air high16)
#define WS_FLAG_OFF   0
#define WS_SUMS_OFF   16
#define WS_PACK_OFF   (16 + 2 * NBLOCKS * (int)sizeof(int))
#define WS_PACK_BYTES (NBLOCKS * BLOCK * (int)sizeof(unsigned int))
#define WS_NEEDED     ((size_t)WS_PACK_OFF + (size_t)WS_PACK_BYTES)

// ---------------------------------------------------------------------------
// Mask decode helpers: 16 consecutive elements -> 16-bit mask
// ---------------------------------------------------------------------------
__device__ __forceinline__ unsigned int decode16_i32(const unsigned int* p) {
    unsigned int bits = 0;
    #pragma unroll
    for (int q = 0; q < 4; ++q) {
        uint4 v = ((const uint4*)p)[q];
        bits |= (v.x ? 1u : 0u) << (4 * q + 0);
        bits |= (v.y ? 1u : 0u) << (4 * q + 1);
        bits |= (v.z ? 1u : 0u) << (4 * q + 2);
        bits |= (v.w ? 1u : 0u) << (4 * q + 3);
    }
    return bits;
}

__device__ __forceinline__ unsigned int decode16_u8(const uint8_t* p) {
    const ulonglong2 v = *(const ulonglong2*)p;
    unsigned int bits = 0;
    #pragma unroll
    for (int j = 0; j < 8; ++j) bits |= (unsigned int)((v.x >> (8 * j)) & 1ull) << j;
    #pragma unroll
    for (int j = 0; j < 8; ++j) bits |= (unsigned int)((v.y >> (8 * j)) & 1ull) << (8 + j);
    return bits;
}

__device__ __forceinline__ unsigned int decode16(const void* m, size_t elem_base, int is_i32) {
    return is_i32 ? decode16_i32((const unsigned int*)m + elem_base)
                  : decode16_u8((const uint8_t*)m + elem_base);
}

// ---------------------------------------------------------------------------
// Kernel 0: detect mask element width. int32 0/1 -> bytes at off%4!=0 all zero.
// ---------------------------------------------------------------------------
__global__ __launch_bounds__(64) void detect_kernel(const unsigned long long* m,
                                                    int* flag) {
    const int lane = threadIdx.x;
    unsigned long long o = 0;
    #pragma unroll
    for (int q = 0; q < 8; ++q) o |= m[lane * 8 + q];   // first 4096 bytes
    #pragma unroll
    for (int d = 32; d > 0; d >>= 1) o |= __shfl_down(o, d, 64);
    if (lane == 0) *flag = ((o & 0xFFFFFFFEFFFFFFFEull) == 0ull) ? 1 : 0;
}

// ---------------------------------------------------------------------------
// Kernel 1: per-block mask popcounts + bit-repack
// ---------------------------------------------------------------------------
__global__ __launch_bounds__(BLOCK) void reduce_pack_kernel(
    const void* __restrict__ ms,
    const void* __restrict__ ma,
    const int* __restrict__ flag,
    int* __restrict__ sums_s,
    int* __restrict__ sums_a,
    unsigned int* __restrict__ packed,   // may be null
    int have_pack)
{
    const int blk  = blockIdx.x;
    const int tid  = threadIdx.x;
    const int lane = tid & 63;
    const size_t base = (size_t)blk * ELEMS_PER_BLOCK + (size_t)tid * ELEMS_PER_THREAD;
    const int is_i32 = *flag;

    const unsigned int bits_s = decode16(ms, base, is_i32);
    const unsigned int bits_a = decode16(ma, base, is_i32);

    if (have_pack) packed[blk * BLOCK + tid] = bits_s | (bits_a << 16);

    const int cs = __popc(bits_s);
    const int ca = __popc(bits_a);

    unsigned long long v = ((unsigned long long)(unsigned)ca << 32) | (unsigned)cs;
    #pragma unroll
    for (int d = 32; d > 0; d >>= 1)
        v += __shfl_down(v, d, 64);

    __shared__ unsigned long long wsum[BLOCK / 64];
    if (lane == 0) wsum[tid >> 6] = v;
    __syncthreads();
    if (tid == 0) {
        unsigned long long t = 0;
        #pragma unroll
        for (int w = 0; w < BLOCK / 64; ++w) t += wsum[w];
        sums_s[blk] = (int)(t & 0xffffffffULL);
        sums_a[blk] = (int)(t >> 32);
    }
}

// ---------------------------------------------------------------------------
// Kernel 2: exclusive scan of the 1024 block sums (single block, in place)
// ---------------------------------------------------------------------------
__global__ __launch_bounds__(1024) void scan_kernel(
    int* __restrict__ sums_s,
    int* __restrict__ sums_a)
{
    const int tid = threadIdx.x;
    const unsigned long long v =
        ((unsigned long long)(unsigned)sums_a[tid] << 32) | (unsigned)sums_s[tid];

    __shared__ unsigned long long tmp[NBLOCKS];
    tmp[tid] = v;
    __syncthreads();
    #pragma unroll
    for (int d = 1; d < NBLOCKS; d <<= 1) {
        unsigned long long t = (tid >= d) ? tmp[tid - d] : 0ULL;
        __syncthreads();
        tmp[tid] += t;
        __syncthreads();
    }
    const unsigned long long excl = tmp[tid] - v;
    sums_s[tid] = (int)(excl & 0xffffffffULL);
    sums_a[tid] = (int)(excl >> 32);
}

// ---------------------------------------------------------------------------
// Kernel 3: local prefix + gather + scale + select + vectorized stores
// MODE 0: masks from packed bits. MODE 1: masks re-decoded from raw arrays.
// ---------------------------------------------------------------------------
template <int MODE>
__global__ __launch_bounds__(BLOCK) void scatter_kernel(
    const float* __restrict__ rgb,
    const float* __restrict__ ls,
    const float* __restrict__ la,
    const void* __restrict__ ms,
    const void* __restrict__ ma,
    const int* __restrict__ flag,
    const unsigned int* __restrict__ packed,
    const float* __restrict__ idle_states,
    const int* __restrict__ off_s_arr,
    const int* __restrict__ off_a_arr,
    float* __restrict__ out)
{
    const int blk  = blockIdx.x;
    const int tid  = threadIdx.x;
    const int lane = tid & 63;
    const int wave = tid >> 6;
    const size_t base = (size_t)blk * ELEMS_PER_BLOCK + (size_t)tid * ELEMS_PER_THREAD;

    unsigned int bits_s, bits_a;
    if (MODE == 0) {
        const unsigned int p = packed[blk * BLOCK + tid];
        bits_s = p & 0xffffu;
        bits_a = p >> 16;
    } else {
        const int is_i32 = *flag;
        bits_s = decode16(ms, base, is_i32);
        bits_a = decode16(ma, base, is_i32);
    }

    const int cs = __popc(bits_s);
    const int ca = __popc(bits_a);

    // packed (air<<32 | surface) wave-level inclusive scan via shuffles
    const unsigned long long pack = ((unsigned long long)(unsigned)ca << 32) | (unsigned)cs;
    unsigned long long incl = pack;
    #pragma unroll
    for (int d = 1; d < 64; d <<= 1) {
        unsigned long long t = __shfl_up(incl, d, 64);
        if (lane >= d) incl += t;
    }
    unsigned long long excl = incl - pack;

    __shared__ unsigned long long wtot[BLOCK / 64];
    if (lane == 63) wtot[wave] = incl;
    __syncthreads();
    #pragma unroll
    for (int w = 0; w < BLOCK / 64; ++w)
        if (w < wave) excl += wtot[w];

    int idx_s = off_s_arr[blk] + (int)(excl & 0xffffffffULL);
    int idx_a = off_a_arr[blk] + (int)(excl >> 32);

    // entire block shares one (b,k): N = 32 * ELEMS_PER_BLOCK
    const float idle      = idle_states[blk >> 5];
    const float scale     = 1.0f - idle;
    const float idle_term = idle * NEG_IDLE;

    float orgb[3 * ELEMS_PER_THREAD];
    float ols[ELEMS_PER_THREAD];
    float ola[ELEMS_PER_THREAD];

    #pragma unroll
    for (int j = 0; j < ELEMS_PER_THREAD; ++j) {
        const bool bs = (bits_s >> j) & 1u;
        const bool ba = (bits_a >> j) & 1u;

        // Branchless: idx always in-bounds (exclusive prefix <= elem pos < T)
        const float* rp = rgb + (size_t)idx_s * 3;
        const float r0 = rp[0], r1 = rp[1], r2 = rp[2];
        const float lsv = ls[idx_s];
        const float lav = la[idx_a];

        orgb[j * 3 + 0] = bs ? r0 * scale : 0.0f;
        orgb[j * 3 + 1] = bs ? r1 * scale : 0.0f;
        orgb[j * 3 + 2] = bs ? r2 * scale : 0.0f;
        ols[j] = bs ? (lsv * scale + idle_term) : NEG_FILL;
        ola[j] = ba ? (lav * scale + idle_term) : NEG_FILL;

        idx_s += bs ? 1 : 0;
        idx_a += ba ? 1 : 0;
    }

    // Vectorized stores: per-thread contiguous, 16B-aligned regions
    float4* prgb = (float4*)(out + base * 3);
    #pragma unroll
    for (int j = 0; j < 12; ++j) prgb[j] = ((const float4*)orgb)[j];

    float4* pls = (float4*)(out + (size_t)3 * T_TOTAL + base);
    #pragma unroll
    for (int j = 0; j < 4; ++j) pls[j] = ((const float4*)ols)[j];

    float4* pla = (float4*)(out + (size_t)4 * T_TOTAL + base);
    #pragma unroll
    for (int j = 0; j < 4; ++j) pla[j] = ((const float4*)ola)[j];
}

// ---------------------------------------------------------------------------
extern "C" void kernel_launch(void* const* d_in, const int* in_sizes, int n_in,
                              void* d_out, int out_size, void* d_ws, size_t ws_size,
                              hipStream_t stream) {
    const float* rgb  = (const float*)d_in[0];
    const float* ls   = (const float*)d_in[1];
    const float* la   = (const float*)d_in[2];
    const void*  ms   = d_in[3];   // bool: int32 (expected) or uint8 — auto-detected
    const void*  ma   = d_in[4];
    const float* idle = (const float*)d_in[5];
    float* out = (float*)d_out;

    uint8_t* ws = (uint8_t*)d_ws;
    int* flag   = (int*)(ws + WS_FLAG_OFF);
    int* sums_s = (int*)(ws + WS_SUMS_OFF);
    int* sums_a = sums_s + NBLOCKS;
    unsigned int* packed = (unsigned int*)(ws + WS_PACK_OFF);
    const int have_pack = (ws_size >= WS_NEEDED) ? 1 : 0;

    detect_kernel<<<1, 64, 0, stream>>>((const unsigned long long*)ms, flag);
    reduce_pack_kernel<<<NBLOCKS, BLOCK, 0, stream>>>(ms, ma, flag, sums_s, sums_a,
                                                      have_pack ? packed : nullptr,
                                                      have_pack);
    scan_kernel<<<1, NBLOCKS, 0, stream>>>(sums_s, sums_a);
    if (have_pack) {
        scatter_kernel<0><<<NBLOCKS, BLOCK, 0, stream>>>(rgb, ls, la, ms, ma, flag,
                                                         packed, idle, sums_s, sums_a, out);
    } else {
        scatter_kernel<1><<<NBLOCKS, BLOCK, 0, stream>>>(rgb, ls, la, ms, ma, flag,
                                                         packed, idle, sums_s, sums_a, out);
    }
}